// Round 17
// baseline (191.042 us; speedup 1.0000x reference)
//
#include <hip/hip_runtime.h>

#define INV_SQRT2f 0.70710678118654752440f

// Analysis filters; synthesis filter f[k] = AF[9-k] (time reversal).
// Polyphase synthesis: out[2q+p] = sum_{j=0..4} AF[9-(2j+p)] * x[(q+2-j) mod Nin]
// Scatter form (verified R3/R11/R14): source idx u -> out[2t+p] with tap AF[2(u-t)+1-p],
// t in [u-4,u] & [0,7].
__constant__ float c_FAR[2][2][10] = {
  {{0.0f, -0.08838834764832f, 0.08838834764832f, 0.69587998903400f, 0.69587998903400f,
    0.08838834764832f, -0.08838834764832f, 0.01122679215254f, 0.01122679215254f, 0.0f},
   {0.0f, -0.01122679215254f, 0.01122679215254f, 0.08838834764832f, 0.08838834764832f,
    -0.69587998903400f, 0.69587998903400f, -0.08838834764832f, -0.08838834764832f, 0.0f}},
  {{0.01122679215254f, 0.01122679215254f, -0.08838834764832f, 0.08838834764832f, 0.69587998903400f,
    0.69587998903400f, 0.08838834764832f, -0.08838834764832f, 0.0f, 0.0f},
   {0.0f, 0.0f, -0.08838834764832f, -0.08838834764832f, 0.69587998903400f,
    -0.69587998903400f, 0.08838834764832f, 0.08838834764832f, 0.01122679215254f, -0.01122679215254f}}
};
__constant__ float c_DUAL[2][2][10] = {
  {{0.03516384f, 0.0f, -0.08832942f, 0.23389032f, 0.76027237f,
    0.58751830f, 0.0f, -0.11430184f, 0.0f, 0.0f},
   {0.0f, 0.0f, -0.11430184f, 0.0f, 0.58751830f,
    -0.76027237f, 0.23389032f, 0.08832942f, 0.0f, -0.03516384f}},
  {{0.0f, 0.0f, -0.11430184f, 0.0f, 0.58751830f,
    0.76027237f, 0.23389032f, -0.08832942f, 0.0f, 0.03516384f},
   {-0.03516384f, 0.0f, 0.08832942f, 0.23389032f, -0.76027237f,
    0.58751830f, 0.0f, -0.11430184f, 0.0f, 0.0f}}
};

#define CS_RSTRIDE 264   // words; 264 % 32 == 8 -> phase-2 reads 2-way (free), writes <=4-way
#define CS_WORDS (2 * 12 * CS_RSTRIDE)

// ================= Stage A: q-shift (128 -> 256) — R16 version, byte-identical =================
__global__ __launch_bounds__(256) void qshift_kernel(
    const float* __restrict__ w2, const float* __restrict__ loT, float* __restrict__ mid)
{
  __shared__ __align__(16) float colsum[CS_WORDS];   // 25344 B

  const int tid = threadIdx.x;
  const int c = tid & 15;
  const int s = tid >> 4;
  const int tw = blockIdx.x;
  const int th = blockIdx.y;
  const int b  = blockIdx.z & 3;
  const int q  = blockIdx.z >> 2;
  const int m = q >> 1, n = q & 1;
  const int j1 = m ^ n;
  const float sgn = m ? -1.0f : 1.0f;
  const int ih0 = th * 8, iw0 = tw * 8;
  const size_t plane = (size_t)128 * 128 * 16;

  // phase-1 identity: wave-aligned role split; threads 192..255 idle in phase 1
  int role, rr;
  const int c2 = tid & 7;
  if (tid < 64)       { role = 0; rr = tid >> 3; }
  else if (tid < 128) { role = 1; rr = (tid & 63) >> 3; }
  else if (tid < 160) { role = 0; rr = 8 + ((tid & 31) >> 3); }
  else                { role = 1; rr = 8 + ((tid & 31) >> 3); }
  const bool p1act = tid < 192;
  const int gr = (ih0 + rr - 2) & 127;
  const int rowoff = (gr << 11) + 2 * c2;   // words: gr*128*16 + 2*c2

  int gco[12];
  #pragma unroll
  for (int x = 0; x < 12; ++x) gco[x] = ((iw0 + x - 2) & 127) << 4;

  if (p1act) {
    float2 S[16];
    #pragma unroll
    for (int i = 0; i < 16; ++i) S[i] = make_float2(0.f, 0.f);
    const float* tl = &c_DUAL[n][0][0];   // LP column taps
    const float* tp = &c_DUAL[n][1][0];   // HP column taps

    if (role == 0) {
      // plane P0 = lo (LP taps, no mix)
      {
        const float* pm = loT + ((size_t)(m * 2 + n) * 4 + b) * plane + rowoff;
        float2 v[12];
        #pragma unroll
        for (int x = 0; x < 12; ++x) v[x] = *reinterpret_cast<const float2*>(pm + gco[x]);
        #pragma unroll
        for (int x = 0; x < 12; ++x) {
          #pragma unroll
          for (int d = 0; d < 5; ++d) {
            const int qw = x - d;
            if (qw >= 0 && qw <= 7) {
              S[2 * qw].x     += tl[1 + 2 * d] * v[x].x;
              S[2 * qw].y     += tl[1 + 2 * d] * v[x].y;
              S[2 * qw + 1].x += tl[2 * d]     * v[x].x;
              S[2 * qw + 1].y += tl[2 * d]     * v[x].y;
            }
          }
        }
      }
      // plane P1 = (A0 +/- B0)*k (HP taps)
      {
        const float* pa = w2 + ((size_t)((0 * 2 + j1) * 3 + 0) * 4 + b) * plane + rowoff;
        const float* pb = w2 + ((size_t)((1 * 2 + (1 ^ j1)) * 3 + 0) * 4 + b) * plane + rowoff;
        float2 av[12], bv[12];
        #pragma unroll
        for (int x = 0; x < 12; ++x) {
          av[x] = *reinterpret_cast<const float2*>(pa + gco[x]);
          bv[x] = *reinterpret_cast<const float2*>(pb + gco[x]);
        }
        #pragma unroll
        for (int x = 0; x < 12; ++x) {
          float2 mv;
          mv.x = (av[x].x + sgn * bv[x].x) * INV_SQRT2f;
          mv.y = (av[x].y + sgn * bv[x].y) * INV_SQRT2f;
          #pragma unroll
          for (int d = 0; d < 5; ++d) {
            const int qw = x - d;
            if (qw >= 0 && qw <= 7) {
              S[2 * qw].x     += tp[1 + 2 * d] * mv.x;
              S[2 * qw].y     += tp[1 + 2 * d] * mv.y;
              S[2 * qw + 1].x += tp[2 * d]     * mv.x;
              S[2 * qw + 1].y += tp[2 * d]     * mv.y;
            }
          }
        }
      }
    } else {
      // plane P2 = (A1 +/- B1)*k (LP taps)
      {
        const float* pa = w2 + ((size_t)((0 * 2 + j1) * 3 + 1) * 4 + b) * plane + rowoff;
        const float* pb = w2 + ((size_t)((1 * 2 + (1 ^ j1)) * 3 + 1) * 4 + b) * plane + rowoff;
        float2 av[12], bv[12];
        #pragma unroll
        for (int x = 0; x < 12; ++x) {
          av[x] = *reinterpret_cast<const float2*>(pa + gco[x]);
          bv[x] = *reinterpret_cast<const float2*>(pb + gco[x]);
        }
        #pragma unroll
        for (int x = 0; x < 12; ++x) {
          float2 mv;
          mv.x = (av[x].x + sgn * bv[x].x) * INV_SQRT2f;
          mv.y = (av[x].y + sgn * bv[x].y) * INV_SQRT2f;
          #pragma unroll
          for (int d = 0; d < 5; ++d) {
            const int qw = x - d;
            if (qw >= 0 && qw <= 7) {
              S[2 * qw].x     += tl[1 + 2 * d] * mv.x;
              S[2 * qw].y     += tl[1 + 2 * d] * mv.y;
              S[2 * qw + 1].x += tl[2 * d]     * mv.x;
              S[2 * qw + 1].y += tl[2 * d]     * mv.y;
            }
          }
        }
      }
      // plane P3 = (A2 +/- B2)*k (HP taps)
      {
        const float* pa = w2 + ((size_t)((0 * 2 + j1) * 3 + 2) * 4 + b) * plane + rowoff;
        const float* pb = w2 + ((size_t)((1 * 2 + (1 ^ j1)) * 3 + 2) * 4 + b) * plane + rowoff;
        float2 av[12], bv[12];
        #pragma unroll
        for (int x = 0; x < 12; ++x) {
          av[x] = *reinterpret_cast<const float2*>(pa + gco[x]);
          bv[x] = *reinterpret_cast<const float2*>(pb + gco[x]);
        }
        #pragma unroll
        for (int x = 0; x < 12; ++x) {
          float2 mv;
          mv.x = (av[x].x + sgn * bv[x].x) * INV_SQRT2f;
          mv.y = (av[x].y + sgn * bv[x].y) * INV_SQRT2f;
          #pragma unroll
          for (int d = 0; d < 5; ++d) {
            const int qw = x - d;
            if (qw >= 0 && qw <= 7) {
              S[2 * qw].x     += tp[1 + 2 * d] * mv.x;
              S[2 * qw].y     += tp[1 + 2 * d] * mv.y;
              S[2 * qw + 1].x += tp[2 * d]     * mv.x;
              S[2 * qw + 1].y += tp[2 * d]     * mv.y;
            }
          }
        }
      }
    }
    float* dst = &colsum[(role * 12 + rr) * CS_RSTRIDE + 2 * c2];
    #pragma unroll
    for (int nw = 0; nw < 16; ++nw)
      *reinterpret_cast<float2*>(dst + nw * 16) = S[nw];
  }
  __syncthreads();

  // phase 2: row gather (R7's proven code), write mid
  float lo2[12], h2[12];
  #pragma unroll
  for (int r = 0; r < 12; ++r) {
    lo2[r] = colsum[(0 * 12 + r) * CS_RSTRIDE + s * 16 + c];
    h2[r]  = colsum[(1 * 12 + r) * CS_RSTRIDE + s * 16 + c];
  }
  float* outQ = mid + ((size_t)q * 4 + b) * (size_t)(256 * 256 * 16);
  #pragma unroll
  for (int nh = 0; nh < 16; ++nh) {
    const int ph = nh & 1, qh = nh >> 1;
    float v = 0.f;
    #pragma unroll
    for (int j = 0; j < 5; ++j) {
      v += c_DUAL[m][0][9 - (2 * j + ph)] * lo2[qh + 4 - j]
         + c_DUAL[m][1][9 - (2 * j + ph)] * h2[qh + 4 - j];
    }
    outQ[(((size_t)(ih0 * 2 + nh)) * 256 + (size_t)(iw0 * 2 + s)) * 16 + c] = v;
  }
}

// ================= Stage B: Farras (256 -> 512) — R14 inner code, TWO tiles per block =================
// 512 threads: tile = tid>>8 picks the x-adjacent output tile; inner 256 threads run the
// R14/R16 farras code verbatim on colsum[tile]. Both tiles' phase-1 loads share each barrier
// window -> 2x memory-level parallelism per window; zero extra per-thread state (VGPR ~64).
__global__ __launch_bounds__(512) void farras_kernel(
    const float* __restrict__ w1, const float* __restrict__ mid, float* __restrict__ out)
{
  __shared__ __align__(16) float colsum2[2 * CS_WORDS];   // 50688 B

  const int tid512 = threadIdx.x;
  const int tile = tid512 >> 8;
  const int tid = tid512 & 255;
  float* const colsum = &colsum2[tile * CS_WORDS];

  const int c = tid & 15;
  const int s = tid >> 4;          // phase-2 output column nw
  const int tw = blockIdx.x * 2 + tile;
  const int th = blockIdx.y;
  const int b  = blockIdx.z;
  const int ih0 = th * 8, iw0 = tw * 8;
  const size_t plane = (size_t)256 * 256 * 16;

  // phase-1 identity: wave-aligned role split; inner threads 192..255 idle in phase 1
  int role, rr;
  const int c2 = tid & 7;
  if (tid < 64)       { role = 0; rr = tid >> 3; }
  else if (tid < 128) { role = 1; rr = (tid & 63) >> 3; }
  else if (tid < 160) { role = 0; rr = 8 + ((tid & 31) >> 3); }
  else                { role = 1; rr = 8 + ((tid & 31) >> 3); }
  const bool p1act = tid < 192;
  const int gr = (ih0 + rr - 2) & 255;
  const int rowoff = (gr << 12) + 2 * c2;   // words: gr*256*16 + 2*c2

  int gco[12];                              // per-x column offsets (words)
  #pragma unroll
  for (int x = 0; x < 12; ++x) gco[x] = ((iw0 + x - 2) & 255) << 4;

  float acc[16];
  #pragma unroll
  for (int i = 0; i < 16; ++i) acc[i] = 0.f;

  #pragma unroll 1
  for (int q = 0; q < 4; ++q) {
    const int m = q >> 1, n = q & 1;
    const int j1 = m ^ n;
    const float sgn = m ? -1.0f : 1.0f;

    if (p1act) {
      float2 S[16];
      #pragma unroll
      for (int i = 0; i < 16; ++i) S[i] = make_float2(0.f, 0.f);
      const float* tl = &c_FAR[n][0][0];   // LP column taps
      const float* tp = &c_FAR[n][1][0];   // HP column taps

      if (role == 0) {
        // plane P0 = mid (LP taps)
        {
          const float* pm = mid + ((size_t)q * 4 + b) * plane + rowoff;
          float2 v[12];
          #pragma unroll
          for (int x = 0; x < 12; ++x) v[x] = *reinterpret_cast<const float2*>(pm + gco[x]);
          #pragma unroll
          for (int x = 0; x < 12; ++x) {
            #pragma unroll
            for (int d = 0; d < 5; ++d) {
              const int qw = x - d;
              if (qw >= 0 && qw <= 7) {
                S[2 * qw].x     += tl[1 + 2 * d] * v[x].x;
                S[2 * qw].y     += tl[1 + 2 * d] * v[x].y;
                S[2 * qw + 1].x += tl[2 * d]     * v[x].x;
                S[2 * qw + 1].y += tl[2 * d]     * v[x].y;
              }
            }
          }
        }
        // plane P1 = (A0 +/- B0)*k (HP taps)
        {
          const float* pa = w1 + ((size_t)((0 * 2 + j1) * 3 + 0) * 4 + b) * plane + rowoff;
          const float* pb = w1 + ((size_t)((1 * 2 + (1 ^ j1)) * 3 + 0) * 4 + b) * plane + rowoff;
          float2 av[12], bv[12];
          #pragma unroll
          for (int x = 0; x < 12; ++x) {
            av[x] = *reinterpret_cast<const float2*>(pa + gco[x]);
            bv[x] = *reinterpret_cast<const float2*>(pb + gco[x]);
          }
          #pragma unroll
          for (int x = 0; x < 12; ++x) {
            float2 mv;
            mv.x = (av[x].x + sgn * bv[x].x) * INV_SQRT2f;
            mv.y = (av[x].y + sgn * bv[x].y) * INV_SQRT2f;
            #pragma unroll
            for (int d = 0; d < 5; ++d) {
              const int qw = x - d;
              if (qw >= 0 && qw <= 7) {
                S[2 * qw].x     += tp[1 + 2 * d] * mv.x;
                S[2 * qw].y     += tp[1 + 2 * d] * mv.y;
                S[2 * qw + 1].x += tp[2 * d]     * mv.x;
                S[2 * qw + 1].y += tp[2 * d]     * mv.y;
              }
            }
          }
        }
      } else {
        // plane P2 = (A1 +/- B1)*k (LP taps)
        {
          const float* pa = w1 + ((size_t)((0 * 2 + j1) * 3 + 1) * 4 + b) * plane + rowoff;
          const float* pb = w1 + ((size_t)((1 * 2 + (1 ^ j1)) * 3 + 1) * 4 + b) * plane + rowoff;
          float2 av[12], bv[12];
          #pragma unroll
          for (int x = 0; x < 12; ++x) {
            av[x] = *reinterpret_cast<const float2*>(pa + gco[x]);
            bv[x] = *reinterpret_cast<const float2*>(pb + gco[x]);
          }
          #pragma unroll
          for (int x = 0; x < 12; ++x) {
            float2 mv;
            mv.x = (av[x].x + sgn * bv[x].x) * INV_SQRT2f;
            mv.y = (av[x].y + sgn * bv[x].y) * INV_SQRT2f;
            #pragma unroll
            for (int d = 0; d < 5; ++d) {
              const int qw = x - d;
              if (qw >= 0 && qw <= 7) {
                S[2 * qw].x     += tl[1 + 2 * d] * mv.x;
                S[2 * qw].y     += tl[1 + 2 * d] * mv.y;
                S[2 * qw + 1].x += tl[2 * d]     * mv.x;
                S[2 * qw + 1].y += tl[2 * d]     * mv.y;
              }
            }
          }
        }
        // plane P3 = (A2 +/- B2)*k (HP taps)
        {
          const float* pa = w1 + ((size_t)((0 * 2 + j1) * 3 + 2) * 4 + b) * plane + rowoff;
          const float* pb = w1 + ((size_t)((1 * 2 + (1 ^ j1)) * 3 + 2) * 4 + b) * plane + rowoff;
          float2 av[12], bv[12];
          #pragma unroll
          for (int x = 0; x < 12; ++x) {
            av[x] = *reinterpret_cast<const float2*>(pa + gco[x]);
            bv[x] = *reinterpret_cast<const float2*>(pb + gco[x]);
          }
          #pragma unroll
          for (int x = 0; x < 12; ++x) {
            float2 mv;
            mv.x = (av[x].x + sgn * bv[x].x) * INV_SQRT2f;
            mv.y = (av[x].y + sgn * bv[x].y) * INV_SQRT2f;
            #pragma unroll
            for (int d = 0; d < 5; ++d) {
              const int qw = x - d;
              if (qw >= 0 && qw <= 7) {
                S[2 * qw].x     += tp[1 + 2 * d] * mv.x;
                S[2 * qw].y     += tp[1 + 2 * d] * mv.y;
                S[2 * qw + 1].x += tp[2 * d]     * mv.x;
                S[2 * qw + 1].y += tp[2 * d]     * mv.y;
              }
            }
          }
        }
      }
      // write S -> colsum[role][rr][nw][c2 pair]
      float* dst = &colsum[(role * 12 + rr) * CS_RSTRIDE + 2 * c2];
      #pragma unroll
      for (int nw = 0; nw < 16; ++nw)
        *reinterpret_cast<float2*>(dst + nw * 16) = S[nw];
    }
    __syncthreads();

    // phase 2: row pass in registers (R7's proven gather)
    {
      float lo2[12], h2[12];
      #pragma unroll
      for (int r = 0; r < 12; ++r) {
        lo2[r] = colsum[(0 * 12 + r) * CS_RSTRIDE + s * 16 + c];
        h2[r]  = colsum[(1 * 12 + r) * CS_RSTRIDE + s * 16 + c];
      }
      #pragma unroll
      for (int nh = 0; nh < 16; ++nh) {
        const int ph = nh & 1, qh = nh >> 1;
        float v = 0.f;
        #pragma unroll
        for (int j = 0; j < 5; ++j) {
          v += c_FAR[m][0][9 - (2 * j + ph)] * lo2[qh + 4 - j]
             + c_FAR[m][1][9 - (2 * j + ph)] * h2[qh + 4 - j];
        }
        acc[nh] += v;
      }
    }
    __syncthreads();   // before next quadrant overwrites colsum
  }

  #pragma unroll
  for (int nh = 0; nh < 16; ++nh) {
    size_t gh = (size_t)(ih0 * 2 + nh);
    size_t gw = (size_t)(iw0 * 2 + s);
    out[(((size_t)b * 512 + gh) * 512 + gw) * 16 + c] = acc[nh] * 0.5f;
  }
}

extern "C" void kernel_launch(void* const* d_in, const int* in_sizes, int n_in,
                              void* d_out, int out_size, void* d_ws, size_t ws_size,
                              hipStream_t stream) {
  const float* w1 = (const float*)d_in[0];   // [2,2,3,4,256,256,16]
  const float* w2 = (const float*)d_in[1];   // [2,2,3,4,128,128,16]
  const float* lo = (const float*)d_in[2];   // [2,2,4,128,128,16]
  float* out = (float*)d_out;                // [4,512,512,16]
  float* mid = (float*)d_ws;                 // [4 quadrants][4][256][256][16] = 64 MiB

  qshift_kernel<<<dim3(16, 16, 16), 256, 0, stream>>>(w2, lo, mid);
  farras_kernel<<<dim3(16, 32, 4), 512, 0, stream>>>(w1, mid, out);
}

// Round 18
// 148.464 us; speedup vs baseline: 1.2868x; 1.2868x over previous
//
#include <hip/hip_runtime.h>
#include <hip/hip_fp16.h>

#define INV_SQRT2f 0.70710678118654752440f

// Analysis filters; synthesis filter f[k] = AF[9-k] (time reversal).
// Polyphase synthesis: out[2q+p] = sum_{j=0..4} AF[9-(2j+p)] * x[(q+2-j) mod Nin]
// Scatter form (verified R3/R11/R14): source idx u -> out[2t+p] with tap AF[2(u-t)+1-p],
// t in [u-4,u] & [0,7].
__constant__ float c_FAR[2][2][10] = {
  {{0.0f, -0.08838834764832f, 0.08838834764832f, 0.69587998903400f, 0.69587998903400f,
    0.08838834764832f, -0.08838834764832f, 0.01122679215254f, 0.01122679215254f, 0.0f},
   {0.0f, -0.01122679215254f, 0.01122679215254f, 0.08838834764832f, 0.08838834764832f,
    -0.69587998903400f, 0.69587998903400f, -0.08838834764832f, -0.08838834764832f, 0.0f}},
  {{0.01122679215254f, 0.01122679215254f, -0.08838834764832f, 0.08838834764832f, 0.69587998903400f,
    0.69587998903400f, 0.08838834764832f, -0.08838834764832f, 0.0f, 0.0f},
   {0.0f, 0.0f, -0.08838834764832f, -0.08838834764832f, 0.69587998903400f,
    -0.69587998903400f, 0.08838834764832f, 0.08838834764832f, 0.01122679215254f, -0.01122679215254f}}
};
__constant__ float c_DUAL[2][2][10] = {
  {{0.03516384f, 0.0f, -0.08832942f, 0.23389032f, 0.76027237f,
    0.58751830f, 0.0f, -0.11430184f, 0.0f, 0.0f},
   {0.0f, 0.0f, -0.11430184f, 0.0f, 0.58751830f,
    -0.76027237f, 0.23389032f, 0.08832942f, 0.0f, -0.03516384f}},
  {{0.0f, 0.0f, -0.11430184f, 0.0f, 0.58751830f,
    0.76027237f, 0.23389032f, -0.08832942f, 0.0f, 0.03516384f},
   {-0.03516384f, 0.0f, 0.08832942f, 0.23389032f, -0.76027237f,
    0.58751830f, 0.0f, -0.11430184f, 0.0f, 0.0f}}
};

#define CS_RSTRIDE 264   // words; 264 % 32 == 8 -> phase-2 reads 2-way (free), writes <=4-way
#define CS_WORDS (2 * 12 * CS_RSTRIDE)

// ================= Stage A: q-shift (128 -> 256) — R16 structure; mid stored fp16 =================
__global__ __launch_bounds__(256) void qshift_kernel(
    const float* __restrict__ w2, const float* __restrict__ loT, __half* __restrict__ mid)
{
  __shared__ __align__(16) float colsum[CS_WORDS];   // 25344 B

  const int tid = threadIdx.x;
  const int c = tid & 15;
  const int s = tid >> 4;
  const int tw = blockIdx.x;
  const int th = blockIdx.y;
  const int b  = blockIdx.z & 3;
  const int q  = blockIdx.z >> 2;
  const int m = q >> 1, n = q & 1;
  const int j1 = m ^ n;
  const float sgn = m ? -1.0f : 1.0f;
  const int ih0 = th * 8, iw0 = tw * 8;
  const size_t plane = (size_t)128 * 128 * 16;

  // phase-1 identity: wave-aligned role split; threads 192..255 idle in phase 1
  int role, rr;
  const int c2 = tid & 7;
  if (tid < 64)       { role = 0; rr = tid >> 3; }
  else if (tid < 128) { role = 1; rr = (tid & 63) >> 3; }
  else if (tid < 160) { role = 0; rr = 8 + ((tid & 31) >> 3); }
  else                { role = 1; rr = 8 + ((tid & 31) >> 3); }
  const bool p1act = tid < 192;
  const int gr = (ih0 + rr - 2) & 127;
  const int rowoff = (gr << 11) + 2 * c2;   // words: gr*128*16 + 2*c2

  int gco[12];
  #pragma unroll
  for (int x = 0; x < 12; ++x) gco[x] = ((iw0 + x - 2) & 127) << 4;

  if (p1act) {
    float2 S[16];
    #pragma unroll
    for (int i = 0; i < 16; ++i) S[i] = make_float2(0.f, 0.f);
    const float* tl = &c_DUAL[n][0][0];   // LP column taps
    const float* tp = &c_DUAL[n][1][0];   // HP column taps

    if (role == 0) {
      // plane P0 = lo (LP taps, no mix)
      {
        const float* pm = loT + ((size_t)(m * 2 + n) * 4 + b) * plane + rowoff;
        float2 v[12];
        #pragma unroll
        for (int x = 0; x < 12; ++x) v[x] = *reinterpret_cast<const float2*>(pm + gco[x]);
        #pragma unroll
        for (int x = 0; x < 12; ++x) {
          #pragma unroll
          for (int d = 0; d < 5; ++d) {
            const int qw = x - d;
            if (qw >= 0 && qw <= 7) {
              S[2 * qw].x     += tl[1 + 2 * d] * v[x].x;
              S[2 * qw].y     += tl[1 + 2 * d] * v[x].y;
              S[2 * qw + 1].x += tl[2 * d]     * v[x].x;
              S[2 * qw + 1].y += tl[2 * d]     * v[x].y;
            }
          }
        }
      }
      // plane P1 = (A0 +/- B0)*k (HP taps)
      {
        const float* pa = w2 + ((size_t)((0 * 2 + j1) * 3 + 0) * 4 + b) * plane + rowoff;
        const float* pb = w2 + ((size_t)((1 * 2 + (1 ^ j1)) * 3 + 0) * 4 + b) * plane + rowoff;
        float2 av[12], bv[12];
        #pragma unroll
        for (int x = 0; x < 12; ++x) {
          av[x] = *reinterpret_cast<const float2*>(pa + gco[x]);
          bv[x] = *reinterpret_cast<const float2*>(pb + gco[x]);
        }
        #pragma unroll
        for (int x = 0; x < 12; ++x) {
          float2 mv;
          mv.x = (av[x].x + sgn * bv[x].x) * INV_SQRT2f;
          mv.y = (av[x].y + sgn * bv[x].y) * INV_SQRT2f;
          #pragma unroll
          for (int d = 0; d < 5; ++d) {
            const int qw = x - d;
            if (qw >= 0 && qw <= 7) {
              S[2 * qw].x     += tp[1 + 2 * d] * mv.x;
              S[2 * qw].y     += tp[1 + 2 * d] * mv.y;
              S[2 * qw + 1].x += tp[2 * d]     * mv.x;
              S[2 * qw + 1].y += tp[2 * d]     * mv.y;
            }
          }
        }
      }
    } else {
      // plane P2 = (A1 +/- B1)*k (LP taps)
      {
        const float* pa = w2 + ((size_t)((0 * 2 + j1) * 3 + 1) * 4 + b) * plane + rowoff;
        const float* pb = w2 + ((size_t)((1 * 2 + (1 ^ j1)) * 3 + 1) * 4 + b) * plane + rowoff;
        float2 av[12], bv[12];
        #pragma unroll
        for (int x = 0; x < 12; ++x) {
          av[x] = *reinterpret_cast<const float2*>(pa + gco[x]);
          bv[x] = *reinterpret_cast<const float2*>(pb + gco[x]);
        }
        #pragma unroll
        for (int x = 0; x < 12; ++x) {
          float2 mv;
          mv.x = (av[x].x + sgn * bv[x].x) * INV_SQRT2f;
          mv.y = (av[x].y + sgn * bv[x].y) * INV_SQRT2f;
          #pragma unroll
          for (int d = 0; d < 5; ++d) {
            const int qw = x - d;
            if (qw >= 0 && qw <= 7) {
              S[2 * qw].x     += tl[1 + 2 * d] * mv.x;
              S[2 * qw].y     += tl[1 + 2 * d] * mv.y;
              S[2 * qw + 1].x += tl[2 * d]     * mv.x;
              S[2 * qw + 1].y += tl[2 * d]     * mv.y;
            }
          }
        }
      }
      // plane P3 = (A2 +/- B2)*k (HP taps)
      {
        const float* pa = w2 + ((size_t)((0 * 2 + j1) * 3 + 2) * 4 + b) * plane + rowoff;
        const float* pb = w2 + ((size_t)((1 * 2 + (1 ^ j1)) * 3 + 2) * 4 + b) * plane + rowoff;
        float2 av[12], bv[12];
        #pragma unroll
        for (int x = 0; x < 12; ++x) {
          av[x] = *reinterpret_cast<const float2*>(pa + gco[x]);
          bv[x] = *reinterpret_cast<const float2*>(pb + gco[x]);
        }
        #pragma unroll
        for (int x = 0; x < 12; ++x) {
          float2 mv;
          mv.x = (av[x].x + sgn * bv[x].x) * INV_SQRT2f;
          mv.y = (av[x].y + sgn * bv[x].y) * INV_SQRT2f;
          #pragma unroll
          for (int d = 0; d < 5; ++d) {
            const int qw = x - d;
            if (qw >= 0 && qw <= 7) {
              S[2 * qw].x     += tp[1 + 2 * d] * mv.x;
              S[2 * qw].y     += tp[1 + 2 * d] * mv.y;
              S[2 * qw + 1].x += tp[2 * d]     * mv.x;
              S[2 * qw + 1].y += tp[2 * d]     * mv.y;
            }
          }
        }
      }
    }
    float* dst = &colsum[(role * 12 + rr) * CS_RSTRIDE + 2 * c2];
    #pragma unroll
    for (int nw = 0; nw < 16; ++nw)
      *reinterpret_cast<float2*>(dst + nw * 16) = S[nw];
  }
  __syncthreads();

  // phase 2: row gather (R7's proven code), write mid as fp16
  float lo2[12], h2[12];
  #pragma unroll
  for (int r = 0; r < 12; ++r) {
    lo2[r] = colsum[(0 * 12 + r) * CS_RSTRIDE + s * 16 + c];
    h2[r]  = colsum[(1 * 12 + r) * CS_RSTRIDE + s * 16 + c];
  }
  __half* outQ = mid + ((size_t)q * 4 + b) * (size_t)(256 * 256 * 16);
  #pragma unroll
  for (int nh = 0; nh < 16; ++nh) {
    const int ph = nh & 1, qh = nh >> 1;
    float v = 0.f;
    #pragma unroll
    for (int j = 0; j < 5; ++j) {
      v += c_DUAL[m][0][9 - (2 * j + ph)] * lo2[qh + 4 - j]
         + c_DUAL[m][1][9 - (2 * j + ph)] * h2[qh + 4 - j];
    }
    outQ[(((size_t)(ih0 * 2 + nh)) * 256 + (size_t)(iw0 * 2 + s)) * 16 + c] = __float2half(v);
  }
}

// ================= Stage B: Farras (256 -> 512) — R16 source; mid read as fp16 =================
__global__ __launch_bounds__(256) void farras_kernel(
    const float* __restrict__ w1, const __half* __restrict__ mid, float* __restrict__ out)
{
  __shared__ __align__(16) float colsum[CS_WORDS];   // 25344 B

  const int tid = threadIdx.x;
  const int c = tid & 15;
  const int s = tid >> 4;          // phase-2 output column nw
  const int tw = blockIdx.x;
  const int th = blockIdx.y;
  const int b  = blockIdx.z;
  const int ih0 = th * 8, iw0 = tw * 8;
  const size_t plane = (size_t)256 * 256 * 16;

  // phase-1 identity: wave-aligned role split; threads 192..255 idle in phase 1
  int role, rr;
  const int c2 = tid & 7;
  if (tid < 64)       { role = 0; rr = tid >> 3; }
  else if (tid < 128) { role = 1; rr = (tid & 63) >> 3; }
  else if (tid < 160) { role = 0; rr = 8 + ((tid & 31) >> 3); }
  else                { role = 1; rr = 8 + ((tid & 31) >> 3); }
  const bool p1act = tid < 192;
  const int gr = (ih0 + rr - 2) & 255;
  const int rowoff = (gr << 12) + 2 * c2;   // words: gr*256*16 + 2*c2

  int gco[12];                              // wave-uniform per-x column offsets (words)
  #pragma unroll
  for (int x = 0; x < 12; ++x) gco[x] = ((iw0 + x - 2) & 255) << 4;

  float acc[16];
  #pragma unroll
  for (int i = 0; i < 16; ++i) acc[i] = 0.f;

  #pragma unroll 1
  for (int q = 0; q < 4; ++q) {
    const int m = q >> 1, n = q & 1;
    const int j1 = m ^ n;
    const float sgn = m ? -1.0f : 1.0f;

    if (p1act) {
      float2 S[16];
      #pragma unroll
      for (int i = 0; i < 16; ++i) S[i] = make_float2(0.f, 0.f);
      const float* tl = &c_FAR[n][0][0];   // LP column taps
      const float* tp = &c_FAR[n][1][0];   // HP column taps

      if (role == 0) {
        // plane P0 = mid (fp16, LP taps)
        {
          const __half* pm = mid + ((size_t)q * 4 + b) * plane + rowoff;
          __half2 vh[12];
          #pragma unroll
          for (int x = 0; x < 12; ++x) vh[x] = *reinterpret_cast<const __half2*>(pm + gco[x]);
          #pragma unroll
          for (int x = 0; x < 12; ++x) {
            const float2 v = __half22float2(vh[x]);
            #pragma unroll
            for (int d = 0; d < 5; ++d) {
              const int qw = x - d;
              if (qw >= 0 && qw <= 7) {
                S[2 * qw].x     += tl[1 + 2 * d] * v.x;
                S[2 * qw].y     += tl[1 + 2 * d] * v.y;
                S[2 * qw + 1].x += tl[2 * d]     * v.x;
                S[2 * qw + 1].y += tl[2 * d]     * v.y;
              }
            }
          }
        }
        // plane P1 = (A0 +/- B0)*k (HP taps)
        {
          const float* pa = w1 + ((size_t)((0 * 2 + j1) * 3 + 0) * 4 + b) * plane + rowoff;
          const float* pb = w1 + ((size_t)((1 * 2 + (1 ^ j1)) * 3 + 0) * 4 + b) * plane + rowoff;
          float2 av[12], bv[12];
          #pragma unroll
          for (int x = 0; x < 12; ++x) {
            av[x] = *reinterpret_cast<const float2*>(pa + gco[x]);
            bv[x] = *reinterpret_cast<const float2*>(pb + gco[x]);
          }
          #pragma unroll
          for (int x = 0; x < 12; ++x) {
            float2 mv;
            mv.x = (av[x].x + sgn * bv[x].x) * INV_SQRT2f;
            mv.y = (av[x].y + sgn * bv[x].y) * INV_SQRT2f;
            #pragma unroll
            for (int d = 0; d < 5; ++d) {
              const int qw = x - d;
              if (qw >= 0 && qw <= 7) {
                S[2 * qw].x     += tp[1 + 2 * d] * mv.x;
                S[2 * qw].y     += tp[1 + 2 * d] * mv.y;
                S[2 * qw + 1].x += tp[2 * d]     * mv.x;
                S[2 * qw + 1].y += tp[2 * d]     * mv.y;
              }
            }
          }
        }
      } else {
        // plane P2 = (A1 +/- B1)*k (LP taps)
        {
          const float* pa = w1 + ((size_t)((0 * 2 + j1) * 3 + 1) * 4 + b) * plane + rowoff;
          const float* pb = w1 + ((size_t)((1 * 2 + (1 ^ j1)) * 3 + 1) * 4 + b) * plane + rowoff;
          float2 av[12], bv[12];
          #pragma unroll
          for (int x = 0; x < 12; ++x) {
            av[x] = *reinterpret_cast<const float2*>(pa + gco[x]);
            bv[x] = *reinterpret_cast<const float2*>(pb + gco[x]);
          }
          #pragma unroll
          for (int x = 0; x < 12; ++x) {
            float2 mv;
            mv.x = (av[x].x + sgn * bv[x].x) * INV_SQRT2f;
            mv.y = (av[x].y + sgn * bv[x].y) * INV_SQRT2f;
            #pragma unroll
            for (int d = 0; d < 5; ++d) {
              const int qw = x - d;
              if (qw >= 0 && qw <= 7) {
                S[2 * qw].x     += tl[1 + 2 * d] * mv.x;
                S[2 * qw].y     += tl[1 + 2 * d] * mv.y;
                S[2 * qw + 1].x += tl[2 * d]     * mv.x;
                S[2 * qw + 1].y += tl[2 * d]     * mv.y;
              }
            }
          }
        }
        // plane P3 = (A2 +/- B2)*k (HP taps)
        {
          const float* pa = w1 + ((size_t)((0 * 2 + j1) * 3 + 2) * 4 + b) * plane + rowoff;
          const float* pb = w1 + ((size_t)((1 * 2 + (1 ^ j1)) * 3 + 2) * 4 + b) * plane + rowoff;
          float2 av[12], bv[12];
          #pragma unroll
          for (int x = 0; x < 12; ++x) {
            av[x] = *reinterpret_cast<const float2*>(pa + gco[x]);
            bv[x] = *reinterpret_cast<const float2*>(pb + gco[x]);
          }
          #pragma unroll
          for (int x = 0; x < 12; ++x) {
            float2 mv;
            mv.x = (av[x].x + sgn * bv[x].x) * INV_SQRT2f;
            mv.y = (av[x].y + sgn * bv[x].y) * INV_SQRT2f;
            #pragma unroll
            for (int d = 0; d < 5; ++d) {
              const int qw = x - d;
              if (qw >= 0 && qw <= 7) {
                S[2 * qw].x     += tp[1 + 2 * d] * mv.x;
                S[2 * qw].y     += tp[1 + 2 * d] * mv.y;
                S[2 * qw + 1].x += tp[2 * d]     * mv.x;
                S[2 * qw + 1].y += tp[2 * d]     * mv.y;
              }
            }
          }
        }
      }
      // write S -> colsum[role][rr][nw][c2 pair]
      float* dst = &colsum[(role * 12 + rr) * CS_RSTRIDE + 2 * c2];
      #pragma unroll
      for (int nw = 0; nw < 16; ++nw)
        *reinterpret_cast<float2*>(dst + nw * 16) = S[nw];
    }
    __syncthreads();

    // phase 2: row pass in registers (R7's proven gather)
    {
      float lo2[12], h2[12];
      #pragma unroll
      for (int r = 0; r < 12; ++r) {
        lo2[r] = colsum[(0 * 12 + r) * CS_RSTRIDE + s * 16 + c];
        h2[r]  = colsum[(1 * 12 + r) * CS_RSTRIDE + s * 16 + c];
      }
      #pragma unroll
      for (int nh = 0; nh < 16; ++nh) {
        const int ph = nh & 1, qh = nh >> 1;
        float v = 0.f;
        #pragma unroll
        for (int j = 0; j < 5; ++j) {
          v += c_FAR[m][0][9 - (2 * j + ph)] * lo2[qh + 4 - j]
             + c_FAR[m][1][9 - (2 * j + ph)] * h2[qh + 4 - j];
        }
        acc[nh] += v;
      }
    }
    __syncthreads();   // before next quadrant overwrites colsum
  }

  #pragma unroll
  for (int nh = 0; nh < 16; ++nh) {
    size_t gh = (size_t)(ih0 * 2 + nh);
    size_t gw = (size_t)(iw0 * 2 + s);
    out[(((size_t)b * 512 + gh) * 512 + gw) * 16 + c] = acc[nh] * 0.5f;
  }
}

extern "C" void kernel_launch(void* const* d_in, const int* in_sizes, int n_in,
                              void* d_out, int out_size, void* d_ws, size_t ws_size,
                              hipStream_t stream) {
  const float* w1 = (const float*)d_in[0];   // [2,2,3,4,256,256,16]
  const float* w2 = (const float*)d_in[1];   // [2,2,3,4,128,128,16]
  const float* lo = (const float*)d_in[2];   // [2,2,4,128,128,16]
  float* out = (float*)d_out;                // [4,512,512,16]
  __half* mid = (__half*)d_ws;               // [4 quadrants][4][256][256][16] fp16 = 32 MiB

  qshift_kernel<<<dim3(16, 16, 16), 256, 0, stream>>>(w2, lo, mid);
  farras_kernel<<<dim3(32, 32, 4), 256, 0, stream>>>(w1, mid, out);
}

// Round 19
// 143.602 us; speedup vs baseline: 1.3304x; 1.0339x over previous
//
#include <hip/hip_runtime.h>
#include <hip/hip_fp16.h>

#define INV_SQRT2f 0.70710678118654752440f

// Analysis filters; synthesis filter f[k] = AF[9-k] (time reversal).
// Polyphase synthesis: out[2q+p] = sum_{j=0..4} AF[9-(2j+p)] * x[(q+2-j) mod Nin]
// Scatter form (verified R3/R11/R14): source idx u -> out[2t+p] with tap AF[2(u-t)+1-p],
// t in [u-4,u] & [0,7].
__constant__ float c_FAR[2][2][10] = {
  {{0.0f, -0.08838834764832f, 0.08838834764832f, 0.69587998903400f, 0.69587998903400f,
    0.08838834764832f, -0.08838834764832f, 0.01122679215254f, 0.01122679215254f, 0.0f},
   {0.0f, -0.01122679215254f, 0.01122679215254f, 0.08838834764832f, 0.08838834764832f,
    -0.69587998903400f, 0.69587998903400f, -0.08838834764832f, -0.08838834764832f, 0.0f}},
  {{0.01122679215254f, 0.01122679215254f, -0.08838834764832f, 0.08838834764832f, 0.69587998903400f,
    0.69587998903400f, 0.08838834764832f, -0.08838834764832f, 0.0f, 0.0f},
   {0.0f, 0.0f, -0.08838834764832f, -0.08838834764832f, 0.69587998903400f,
    -0.69587998903400f, 0.08838834764832f, 0.08838834764832f, 0.01122679215254f, -0.01122679215254f}}
};
__constant__ float c_DUAL[2][2][10] = {
  {{0.03516384f, 0.0f, -0.08832942f, 0.23389032f, 0.76027237f,
    0.58751830f, 0.0f, -0.11430184f, 0.0f, 0.0f},
   {0.0f, 0.0f, -0.11430184f, 0.0f, 0.58751830f,
    -0.76027237f, 0.23389032f, 0.08832942f, 0.0f, -0.03516384f}},
  {{0.0f, 0.0f, -0.11430184f, 0.0f, 0.58751830f,
    0.76027237f, 0.23389032f, -0.08832942f, 0.0f, 0.03516384f},
   {-0.03516384f, 0.0f, 0.08832942f, 0.23389032f, -0.76027237f,
    0.58751830f, 0.0f, -0.11430184f, 0.0f, 0.0f}}
};

#define CS_RSTRIDE 264   // words; 264 % 32 == 8 -> phase-2 reads 2-way (free), writes <=4-way
#define CS_WORDS (2 * 12 * CS_RSTRIDE)

// ================= Stage A: q-shift (128 -> 256) — R18 version + XCD swizzle =================
__global__ __launch_bounds__(256) void qshift_kernel(
    const float* __restrict__ w2, const float* __restrict__ loT, __half* __restrict__ mid)
{
  __shared__ __align__(16) float colsum[CS_WORDS];   // 25344 B

  const int tid = threadIdx.x;
  const int c = tid & 15;
  const int s = tid >> 4;
  // XCD-aware swizzle: 4096 blocks, each XCD gets 512 consecutive (bq,th,tw) ids
  int id = ((int)blockIdx.z * 16 + (int)blockIdx.y) * 16 + (int)blockIdx.x;
  id = (id & 7) * 512 + (id >> 3);
  const int tw = id & 15;
  const int th = (id >> 4) & 15;
  const int bq = id >> 8;
  const int b  = bq & 3;
  const int q  = bq >> 2;
  const int m = q >> 1, n = q & 1;
  const int j1 = m ^ n;
  const float sgn = m ? -1.0f : 1.0f;
  const int ih0 = th * 8, iw0 = tw * 8;
  const size_t plane = (size_t)128 * 128 * 16;

  // phase-1 identity: wave-aligned role split; threads 192..255 idle in phase 1
  int role, rr;
  const int c2 = tid & 7;
  if (tid < 64)       { role = 0; rr = tid >> 3; }
  else if (tid < 128) { role = 1; rr = (tid & 63) >> 3; }
  else if (tid < 160) { role = 0; rr = 8 + ((tid & 31) >> 3); }
  else                { role = 1; rr = 8 + ((tid & 31) >> 3); }
  const bool p1act = tid < 192;
  const int gr = (ih0 + rr - 2) & 127;
  const int rowoff = (gr << 11) + 2 * c2;   // words: gr*128*16 + 2*c2

  int gco[12];
  #pragma unroll
  for (int x = 0; x < 12; ++x) gco[x] = ((iw0 + x - 2) & 127) << 4;

  if (p1act) {
    float2 S[16];
    #pragma unroll
    for (int i = 0; i < 16; ++i) S[i] = make_float2(0.f, 0.f);
    const float* tl = &c_DUAL[n][0][0];   // LP column taps
    const float* tp = &c_DUAL[n][1][0];   // HP column taps

    if (role == 0) {
      // plane P0 = lo (LP taps, no mix)
      {
        const float* pm = loT + ((size_t)(m * 2 + n) * 4 + b) * plane + rowoff;
        float2 v[12];
        #pragma unroll
        for (int x = 0; x < 12; ++x) v[x] = *reinterpret_cast<const float2*>(pm + gco[x]);
        #pragma unroll
        for (int x = 0; x < 12; ++x) {
          #pragma unroll
          for (int d = 0; d < 5; ++d) {
            const int qw = x - d;
            if (qw >= 0 && qw <= 7) {
              S[2 * qw].x     += tl[1 + 2 * d] * v[x].x;
              S[2 * qw].y     += tl[1 + 2 * d] * v[x].y;
              S[2 * qw + 1].x += tl[2 * d]     * v[x].x;
              S[2 * qw + 1].y += tl[2 * d]     * v[x].y;
            }
          }
        }
      }
      // plane P1 = (A0 +/- B0)*k (HP taps)
      {
        const float* pa = w2 + ((size_t)((0 * 2 + j1) * 3 + 0) * 4 + b) * plane + rowoff;
        const float* pb = w2 + ((size_t)((1 * 2 + (1 ^ j1)) * 3 + 0) * 4 + b) * plane + rowoff;
        float2 av[12], bv[12];
        #pragma unroll
        for (int x = 0; x < 12; ++x) {
          av[x] = *reinterpret_cast<const float2*>(pa + gco[x]);
          bv[x] = *reinterpret_cast<const float2*>(pb + gco[x]);
        }
        #pragma unroll
        for (int x = 0; x < 12; ++x) {
          float2 mv;
          mv.x = (av[x].x + sgn * bv[x].x) * INV_SQRT2f;
          mv.y = (av[x].y + sgn * bv[x].y) * INV_SQRT2f;
          #pragma unroll
          for (int d = 0; d < 5; ++d) {
            const int qw = x - d;
            if (qw >= 0 && qw <= 7) {
              S[2 * qw].x     += tp[1 + 2 * d] * mv.x;
              S[2 * qw].y     += tp[1 + 2 * d] * mv.y;
              S[2 * qw + 1].x += tp[2 * d]     * mv.x;
              S[2 * qw + 1].y += tp[2 * d]     * mv.y;
            }
          }
        }
      }
    } else {
      // plane P2 = (A1 +/- B1)*k (LP taps)
      {
        const float* pa = w2 + ((size_t)((0 * 2 + j1) * 3 + 1) * 4 + b) * plane + rowoff;
        const float* pb = w2 + ((size_t)((1 * 2 + (1 ^ j1)) * 3 + 1) * 4 + b) * plane + rowoff;
        float2 av[12], bv[12];
        #pragma unroll
        for (int x = 0; x < 12; ++x) {
          av[x] = *reinterpret_cast<const float2*>(pa + gco[x]);
          bv[x] = *reinterpret_cast<const float2*>(pb + gco[x]);
        }
        #pragma unroll
        for (int x = 0; x < 12; ++x) {
          float2 mv;
          mv.x = (av[x].x + sgn * bv[x].x) * INV_SQRT2f;
          mv.y = (av[x].y + sgn * bv[x].y) * INV_SQRT2f;
          #pragma unroll
          for (int d = 0; d < 5; ++d) {
            const int qw = x - d;
            if (qw >= 0 && qw <= 7) {
              S[2 * qw].x     += tl[1 + 2 * d] * mv.x;
              S[2 * qw].y     += tl[1 + 2 * d] * mv.y;
              S[2 * qw + 1].x += tl[2 * d]     * mv.x;
              S[2 * qw + 1].y += tl[2 * d]     * mv.y;
            }
          }
        }
      }
      // plane P3 = (A2 +/- B2)*k (HP taps)
      {
        const float* pa = w2 + ((size_t)((0 * 2 + j1) * 3 + 2) * 4 + b) * plane + rowoff;
        const float* pb = w2 + ((size_t)((1 * 2 + (1 ^ j1)) * 3 + 2) * 4 + b) * plane + rowoff;
        float2 av[12], bv[12];
        #pragma unroll
        for (int x = 0; x < 12; ++x) {
          av[x] = *reinterpret_cast<const float2*>(pa + gco[x]);
          bv[x] = *reinterpret_cast<const float2*>(pb + gco[x]);
        }
        #pragma unroll
        for (int x = 0; x < 12; ++x) {
          float2 mv;
          mv.x = (av[x].x + sgn * bv[x].x) * INV_SQRT2f;
          mv.y = (av[x].y + sgn * bv[x].y) * INV_SQRT2f;
          #pragma unroll
          for (int d = 0; d < 5; ++d) {
            const int qw = x - d;
            if (qw >= 0 && qw <= 7) {
              S[2 * qw].x     += tp[1 + 2 * d] * mv.x;
              S[2 * qw].y     += tp[1 + 2 * d] * mv.y;
              S[2 * qw + 1].x += tp[2 * d]     * mv.x;
              S[2 * qw + 1].y += tp[2 * d]     * mv.y;
            }
          }
        }
      }
    }
    float* dst = &colsum[(role * 12 + rr) * CS_RSTRIDE + 2 * c2];
    #pragma unroll
    for (int nw = 0; nw < 16; ++nw)
      *reinterpret_cast<float2*>(dst + nw * 16) = S[nw];
  }
  __syncthreads();

  // phase 2: row gather (R7's proven code), write mid as fp16
  float lo2[12], h2[12];
  #pragma unroll
  for (int r = 0; r < 12; ++r) {
    lo2[r] = colsum[(0 * 12 + r) * CS_RSTRIDE + s * 16 + c];
    h2[r]  = colsum[(1 * 12 + r) * CS_RSTRIDE + s * 16 + c];
  }
  __half* outQ = mid + ((size_t)q * 4 + b) * (size_t)(256 * 256 * 16);
  #pragma unroll
  for (int nh = 0; nh < 16; ++nh) {
    const int ph = nh & 1, qh = nh >> 1;
    float v = 0.f;
    #pragma unroll
    for (int j = 0; j < 5; ++j) {
      v += c_DUAL[m][0][9 - (2 * j + ph)] * lo2[qh + 4 - j]
         + c_DUAL[m][1][9 - (2 * j + ph)] * h2[qh + 4 - j];
    }
    outQ[(((size_t)(ih0 * 2 + nh)) * 256 + (size_t)(iw0 * 2 + s)) * 16 + c] = __float2half(v);
  }
}

// ================= Stage B: Farras (256 -> 512) — R18 source + XCD swizzle =================
__global__ __launch_bounds__(256) void farras_kernel(
    const float* __restrict__ w1, const __half* __restrict__ mid, float* __restrict__ out)
{
  __shared__ __align__(16) float colsum[CS_WORDS];   // 25344 B

  const int tid = threadIdx.x;
  const int c = tid & 15;
  const int s = tid >> 4;          // phase-2 output column nw
  // XCD-aware swizzle: 4096 blocks, each XCD gets 512 consecutive (b,th,tw) ids
  int id = ((int)blockIdx.z * 32 + (int)blockIdx.y) * 32 + (int)blockIdx.x;
  id = (id & 7) * 512 + (id >> 3);
  const int tw = id & 31;
  const int th = (id >> 5) & 31;
  const int b  = id >> 10;
  const int ih0 = th * 8, iw0 = tw * 8;
  const size_t plane = (size_t)256 * 256 * 16;

  // phase-1 identity: wave-aligned role split; threads 192..255 idle in phase 1
  int role, rr;
  const int c2 = tid & 7;
  if (tid < 64)       { role = 0; rr = tid >> 3; }
  else if (tid < 128) { role = 1; rr = (tid & 63) >> 3; }
  else if (tid < 160) { role = 0; rr = 8 + ((tid & 31) >> 3); }
  else                { role = 1; rr = 8 + ((tid & 31) >> 3); }
  const bool p1act = tid < 192;
  const int gr = (ih0 + rr - 2) & 255;
  const int rowoff = (gr << 12) + 2 * c2;   // words: gr*256*16 + 2*c2

  int gco[12];                              // wave-uniform per-x column offsets (words)
  #pragma unroll
  for (int x = 0; x < 12; ++x) gco[x] = ((iw0 + x - 2) & 255) << 4;

  float acc[16];
  #pragma unroll
  for (int i = 0; i < 16; ++i) acc[i] = 0.f;

  #pragma unroll 1
  for (int q = 0; q < 4; ++q) {
    const int m = q >> 1, n = q & 1;
    const int j1 = m ^ n;
    const float sgn = m ? -1.0f : 1.0f;

    if (p1act) {
      float2 S[16];
      #pragma unroll
      for (int i = 0; i < 16; ++i) S[i] = make_float2(0.f, 0.f);
      const float* tl = &c_FAR[n][0][0];   // LP column taps
      const float* tp = &c_FAR[n][1][0];   // HP column taps

      if (role == 0) {
        // plane P0 = mid (fp16, LP taps)
        {
          const __half* pm = mid + ((size_t)q * 4 + b) * plane + rowoff;
          __half2 vh[12];
          #pragma unroll
          for (int x = 0; x < 12; ++x) vh[x] = *reinterpret_cast<const __half2*>(pm + gco[x]);
          #pragma unroll
          for (int x = 0; x < 12; ++x) {
            const float2 v = __half22float2(vh[x]);
            #pragma unroll
            for (int d = 0; d < 5; ++d) {
              const int qw = x - d;
              if (qw >= 0 && qw <= 7) {
                S[2 * qw].x     += tl[1 + 2 * d] * v.x;
                S[2 * qw].y     += tl[1 + 2 * d] * v.y;
                S[2 * qw + 1].x += tl[2 * d]     * v.x;
                S[2 * qw + 1].y += tl[2 * d]     * v.y;
              }
            }
          }
        }
        // plane P1 = (A0 +/- B0)*k (HP taps)
        {
          const float* pa = w1 + ((size_t)((0 * 2 + j1) * 3 + 0) * 4 + b) * plane + rowoff;
          const float* pb = w1 + ((size_t)((1 * 2 + (1 ^ j1)) * 3 + 0) * 4 + b) * plane + rowoff;
          float2 av[12], bv[12];
          #pragma unroll
          for (int x = 0; x < 12; ++x) {
            av[x] = *reinterpret_cast<const float2*>(pa + gco[x]);
            bv[x] = *reinterpret_cast<const float2*>(pb + gco[x]);
          }
          #pragma unroll
          for (int x = 0; x < 12; ++x) {
            float2 mv;
            mv.x = (av[x].x + sgn * bv[x].x) * INV_SQRT2f;
            mv.y = (av[x].y + sgn * bv[x].y) * INV_SQRT2f;
            #pragma unroll
            for (int d = 0; d < 5; ++d) {
              const int qw = x - d;
              if (qw >= 0 && qw <= 7) {
                S[2 * qw].x     += tp[1 + 2 * d] * mv.x;
                S[2 * qw].y     += tp[1 + 2 * d] * mv.y;
                S[2 * qw + 1].x += tp[2 * d]     * mv.x;
                S[2 * qw + 1].y += tp[2 * d]     * mv.y;
              }
            }
          }
        }
      } else {
        // plane P2 = (A1 +/- B1)*k (LP taps)
        {
          const float* pa = w1 + ((size_t)((0 * 2 + j1) * 3 + 1) * 4 + b) * plane + rowoff;
          const float* pb = w1 + ((size_t)((1 * 2 + (1 ^ j1)) * 3 + 1) * 4 + b) * plane + rowoff;
          float2 av[12], bv[12];
          #pragma unroll
          for (int x = 0; x < 12; ++x) {
            av[x] = *reinterpret_cast<const float2*>(pa + gco[x]);
            bv[x] = *reinterpret_cast<const float2*>(pb + gco[x]);
          }
          #pragma unroll
          for (int x = 0; x < 12; ++x) {
            float2 mv;
            mv.x = (av[x].x + sgn * bv[x].x) * INV_SQRT2f;
            mv.y = (av[x].y + sgn * bv[x].y) * INV_SQRT2f;
            #pragma unroll
            for (int d = 0; d < 5; ++d) {
              const int qw = x - d;
              if (qw >= 0 && qw <= 7) {
                S[2 * qw].x     += tl[1 + 2 * d] * mv.x;
                S[2 * qw].y     += tl[1 + 2 * d] * mv.y;
                S[2 * qw + 1].x += tl[2 * d]     * mv.x;
                S[2 * qw + 1].y += tl[2 * d]     * mv.y;
              }
            }
          }
        }
        // plane P3 = (A2 +/- B2)*k (HP taps)
        {
          const float* pa = w1 + ((size_t)((0 * 2 + j1) * 3 + 2) * 4 + b) * plane + rowoff;
          const float* pb = w1 + ((size_t)((1 * 2 + (1 ^ j1)) * 3 + 2) * 4 + b) * plane + rowoff;
          float2 av[12], bv[12];
          #pragma unroll
          for (int x = 0; x < 12; ++x) {
            av[x] = *reinterpret_cast<const float2*>(pa + gco[x]);
            bv[x] = *reinterpret_cast<const float2*>(pb + gco[x]);
          }
          #pragma unroll
          for (int x = 0; x < 12; ++x) {
            float2 mv;
            mv.x = (av[x].x + sgn * bv[x].x) * INV_SQRT2f;
            mv.y = (av[x].y + sgn * bv[x].y) * INV_SQRT2f;
            #pragma unroll
            for (int d = 0; d < 5; ++d) {
              const int qw = x - d;
              if (qw >= 0 && qw <= 7) {
                S[2 * qw].x     += tp[1 + 2 * d] * mv.x;
                S[2 * qw].y     += tp[1 + 2 * d] * mv.y;
                S[2 * qw + 1].x += tp[2 * d]     * mv.x;
                S[2 * qw + 1].y += tp[2 * d]     * mv.y;
              }
            }
          }
        }
      }
      // write S -> colsum[role][rr][nw][c2 pair]
      float* dst = &colsum[(role * 12 + rr) * CS_RSTRIDE + 2 * c2];
      #pragma unroll
      for (int nw = 0; nw < 16; ++nw)
        *reinterpret_cast<float2*>(dst + nw * 16) = S[nw];
    }
    __syncthreads();

    // phase 2: row pass in registers (R7's proven gather)
    {
      float lo2[12], h2[12];
      #pragma unroll
      for (int r = 0; r < 12; ++r) {
        lo2[r] = colsum[(0 * 12 + r) * CS_RSTRIDE + s * 16 + c];
        h2[r]  = colsum[(1 * 12 + r) * CS_RSTRIDE + s * 16 + c];
      }
      #pragma unroll
      for (int nh = 0; nh < 16; ++nh) {
        const int ph = nh & 1, qh = nh >> 1;
        float v = 0.f;
        #pragma unroll
        for (int j = 0; j < 5; ++j) {
          v += c_FAR[m][0][9 - (2 * j + ph)] * lo2[qh + 4 - j]
             + c_FAR[m][1][9 - (2 * j + ph)] * h2[qh + 4 - j];
        }
        acc[nh] += v;
      }
    }
    __syncthreads();   // before next quadrant overwrites colsum
  }

  #pragma unroll
  for (int nh = 0; nh < 16; ++nh) {
    size_t gh = (size_t)(ih0 * 2 + nh);
    size_t gw = (size_t)(iw0 * 2 + s);
    out[(((size_t)b * 512 + gh) * 512 + gw) * 16 + c] = acc[nh] * 0.5f;
  }
}

extern "C" void kernel_launch(void* const* d_in, const int* in_sizes, int n_in,
                              void* d_out, int out_size, void* d_ws, size_t ws_size,
                              hipStream_t stream) {
  const float* w1 = (const float*)d_in[0];   // [2,2,3,4,256,256,16]
  const float* w2 = (const float*)d_in[1];   // [2,2,3,4,128,128,16]
  const float* lo = (const float*)d_in[2];   // [2,2,4,128,128,16]
  float* out = (float*)d_out;                // [4,512,512,16]
  __half* mid = (__half*)d_ws;               // [4 quadrants][4][256][256][16] fp16 = 32 MiB

  qshift_kernel<<<dim3(16, 16, 16), 256, 0, stream>>>(w2, lo, mid);
  farras_kernel<<<dim3(32, 32, 4), 256, 0, stream>>>(w1, mid, out);
}